// Round 5
// baseline (399.604 us; speedup 1.0000x reference)
//
#include <hip/hip_runtime.h>

#define RES   128
#define FEAT  1024   // map_num(128) * feat_dim(8)
#define NBINS (RES * RES)
#define PPB   8      // points per block in the main kernel

// Native clang vector type: __builtin_nontemporal_store requires it
// (HIP_vector_type float4 is a struct and is rejected).
typedef float float4n __attribute__((ext_vector_type(4)));

// ---------------------------------------------------------------------------
// Morton helpers: 2D-compact cell ordering so sorted points have 2D locality
__device__ __forceinline__ unsigned part1by1(unsigned x)
{
    x &= 0x7F;
    x = (x | (x << 4)) & 0x0F0F;
    x = (x | (x << 2)) & 0x3333;
    x = (x | (x << 1)) & 0x5555;
    return x;
}

__device__ __forceinline__ unsigned cell_code(const float* __restrict__ inputs, int p)
{
    int i0 = (int)floorf(inputs[2 * p + 0] * (float)(RES - 1));
    int i1 = (int)floorf(inputs[2 * p + 1] * (float)(RES - 1));
    return (part1by1((unsigned)i0) << 1) | part1by1((unsigned)i1);
}

// ---------------------------------------------------------------------------
// Pass B: histogram points per Morton cell
__global__ __launch_bounds__(256)
void hist_kernel(const float* __restrict__ inputs, unsigned* __restrict__ hist, int N)
{
    int p = blockIdx.x * 256 + threadIdx.x;
    if (p >= N) return;
    atomicAdd(&hist[cell_code(inputs, p)], 1u);
}

// ---------------------------------------------------------------------------
// Pass C: in-place exclusive scan of 16384 bins (single block, 256 thr x 64)
__global__ __launch_bounds__(256)
void scan_kernel(unsigned* __restrict__ hist)
{
    __shared__ unsigned part[256];
    int t = threadIdx.x;
    int base = t * 64;
    unsigned s = 0;
    for (int k = 0; k < 64; ++k) s += hist[base + k];
    part[t] = s;
    __syncthreads();
    if (t == 0) {
        unsigned run = 0;
        for (int i = 0; i < 256; ++i) { unsigned v = part[i]; part[i] = run; run += v; }
    }
    __syncthreads();
    unsigned run = part[t];
    for (int k = 0; k < 64; ++k) { unsigned v = hist[base + k]; hist[base + k] = run; run += v; }
}

// ---------------------------------------------------------------------------
// Pass D: scatter point indices into Morton-sorted order
__global__ __launch_bounds__(256)
void scatter_kernel(const float* __restrict__ inputs, unsigned* __restrict__ hist,
                    unsigned* __restrict__ order, int N)
{
    int p = blockIdx.x * 256 + threadIdx.x;
    if (p >= N) return;
    unsigned pos = atomicAdd(&hist[cell_code(inputs, p)], 1u);
    order[pos] = (unsigned)p;
}

// ---------------------------------------------------------------------------
// Pass E: bilinear gather-blend in Morton order, PPB points/block.
// Phase 1 prefetches all point metadata (independent loads, breaks dep chain);
// phase 2 gathers + blends + nontemporal-stores (out is never re-read: keep L2
// clean for the embedding table).
__global__ __launch_bounds__(256)
void DenseMap_sorted_kernel(const float* __restrict__ inputs,
                            const float* __restrict__ emb,
                            const unsigned* __restrict__ order,
                            float* __restrict__ out,
                            int N, int chunk)
{
    const int b = blockIdx.x;
    const int c = threadIdx.x;
    // chunk>0: G divisible by 8 -> block b runs on XCD b%8 with a contiguous
    // Morton-sorted sub-range (L2 locality heuristic; correctness-independent)
    const int g = (chunk > 0) ? ((b & 7) * chunk + (b >> 3)) : b;
    const int s0 = g * PPB;

    long  base[PPB];
    float W00[PPB], W01[PPB], W10[PPB], W11[PPB];
    int   pp[PPB];

#pragma unroll
    for (int j = 0; j < PPB; ++j) {
        const int s = s0 + j;
        const int p = (s < N) ? (int)order[s] : -1;
        pp[j] = p;
        if (p >= 0) {
            const float x0 = inputs[2 * p + 0] * (float)(RES - 1);
            const float x1 = inputs[2 * p + 1] * (float)(RES - 1);
            const float f0 = floorf(x0);
            const float f1 = floorf(x1);
            const float xf0 = x0 - f0;
            const float xf1 = x1 - f1;
            base[j] = (long)((int)f0 * RES + (int)f1) * FEAT;
            W00[j] = (1.0f - xf0) * (1.0f - xf1);
            W01[j] = (1.0f - xf0) * xf1;
            W10[j] = xf0 * (1.0f - xf1);
            W11[j] = xf0 * xf1;
        }
    }

#pragma unroll
    for (int j = 0; j < PPB; ++j) {
        const int p = pp[j];
        if (p < 0) continue;
        const long bs = base[j];
        const float4n a  = ((const float4n*)(emb + bs))[c];
        const float4n bb = ((const float4n*)(emb + bs + FEAT))[c];
        const float4n gg = ((const float4n*)(emb + bs + (long)RES * FEAT))[c];
        const float4n hh = ((const float4n*)(emb + bs + (long)RES * FEAT + FEAT))[c];

        float4n r = a * W00[j] + bb * W01[j] + gg * W10[j] + hh * W11[j];

        __builtin_nontemporal_store(r, (float4n*)(out + (long)p * FEAT) + c);
    }
}

// ---------------------------------------------------------------------------
// Fallback: used only if ws is too small for the sort buffers.
__global__ __launch_bounds__(256)
void DenseMap_fallback_kernel(const float* __restrict__ inputs,
                              const float* __restrict__ emb,
                              float* __restrict__ out)
{
    const int p = blockIdx.x;
    const int c = threadIdx.x;

    const float x0 = inputs[2 * p + 0] * (float)(RES - 1);
    const float x1 = inputs[2 * p + 1] * (float)(RES - 1);
    const float f0 = floorf(x0);
    const float f1 = floorf(x1);
    const int   i0 = (int)f0;
    const int   i1 = (int)f1;
    const float xf0 = x0 - f0;
    const float xf1 = x1 - f1;

    const float w00 = (1.0f - xf0) * (1.0f - xf1);
    const float w01 = (1.0f - xf0) * xf1;
    const float w10 = xf0 * (1.0f - xf1);
    const float w11 = xf0 * xf1;

    const long base = (long)(i0 * RES + i1) * FEAT;
    const float4n a = ((const float4n*)(emb + base))[c];
    const float4n b = ((const float4n*)(emb + base + FEAT))[c];
    const float4n g = ((const float4n*)(emb + base + (long)RES * FEAT))[c];
    const float4n h = ((const float4n*)(emb + base + (long)RES * FEAT + FEAT))[c];

    float4n r = a * w00 + b * w01 + g * w10 + h * w11;
    ((float4n*)(out + (long)p * FEAT))[c] = r;
}

extern "C" void kernel_launch(void* const* d_in, const int* in_sizes, int n_in,
                              void* d_out, int out_size, void* d_ws, size_t ws_size,
                              hipStream_t stream)
{
    const float* inputs = (const float*)d_in[0];   // (batch, 2) fp32
    const float* emb    = (const float*)d_in[1];   // (16384, 1024) fp32
    float*       out    = (float*)d_out;           // (batch, 1024) fp32

    const int N = in_sizes[0] / 2;                 // 65536
    const size_t need = (size_t)(NBINS + N) * sizeof(unsigned);

    if (ws_size >= need) {
        unsigned* hist  = (unsigned*)d_ws;         // [NBINS]
        unsigned* order = hist + NBINS;            // [N]

        (void)hipMemsetAsync(hist, 0, NBINS * sizeof(unsigned), stream);
        hist_kernel<<<(N + 255) / 256, 256, 0, stream>>>(inputs, hist, N);
        scan_kernel<<<1, 256, 0, stream>>>(hist);
        scatter_kernel<<<(N + 255) / 256, 256, 0, stream>>>(inputs, hist, order, N);

        const int G = (N + PPB - 1) / PPB;         // groups of PPB points
        const int chunk = (G % 8 == 0) ? (G / 8) : 0;
        DenseMap_sorted_kernel<<<G, 256, 0, stream>>>(inputs, emb, order, out, N, chunk);
    } else {
        DenseMap_fallback_kernel<<<N, 256, 0, stream>>>(inputs, emb, out);
    }
}